// Round 1
// baseline (2308.616 us; speedup 1.0000x reference)
//
#include <hip/hip_runtime.h>
#include <hip/hip_bf16.h>
#include <math.h>

// Problem dims (fixed by setup_inputs)
#define T_TOK 8192
#define D_DIM 4096
#define I_DIM 11008

typedef int v4i __attribute__((ext_vector_type(4)));

typedef const __attribute__((address_space(1))) void* gas_ptr;
typedef __attribute__((address_space(3))) void* las_ptr;

__device__ __forceinline__ void async_load16(const void* g, void* l) {
    __builtin_amdgcn_global_load_lds((gas_ptr)g, (las_ptr)l, 16, 0, 0);
}

__device__ __forceinline__ int q8(float v, float s) {
    float q = rintf(v / s);              // round-half-even, matches jnp.round
    q = fminf(fmaxf(q, -127.0f), 127.0f);
    return ((int)q) & 0xff;
}

// ---------------------------------------------------------------------------
// Kernel A: RMSNorm + per-token int8 quant.  1 block (256 thr) per token row.
// Also zero-inits the h-amax accumulator for this token.
// ---------------------------------------------------------------------------
__global__ void rmsnorm_quant(const float* __restrict__ x, const float* __restrict__ w,
                              char* __restrict__ q, float* __restrict__ s,
                              unsigned* __restrict__ amax_h) {
    __shared__ float red[4];
    const int t = blockIdx.x, tid = threadIdx.x;
    const float4* xr = (const float4*)(x + (size_t)t * D_DIM);
    const float4* wr = (const float4*)w;

    float4 xv[4];
    float ss = 0.0f;
#pragma unroll
    for (int j = 0; j < 4; j++) {
        float4 v = xr[j * 256 + tid];
        xv[j] = v;
        ss += v.x * v.x + v.y * v.y + v.z * v.z + v.w * v.w;
    }
#pragma unroll
    for (int m = 32; m >= 1; m >>= 1) ss += __shfl_xor(ss, m, 64);
    if ((tid & 63) == 0) red[tid >> 6] = ss;
    __syncthreads();
    ss = (red[0] + red[1]) + (red[2] + red[3]);
    const float rstd = 1.0f / sqrtf(ss / (float)D_DIM + 1e-6f);

    float am = 0.0f;
#pragma unroll
    for (int j = 0; j < 4; j++) {
        float4 v = xv[j];
        float4 wv = wr[j * 256 + tid];
        v.x *= rstd * wv.x; v.y *= rstd * wv.y;
        v.z *= rstd * wv.z; v.w *= rstd * wv.w;
        xv[j] = v;
        am = fmaxf(am, fmaxf(fmaxf(fabsf(v.x), fabsf(v.y)), fmaxf(fabsf(v.z), fabsf(v.w))));
    }
    __syncthreads();   // red[] reuse
#pragma unroll
    for (int m = 32; m >= 1; m >>= 1) am = fmaxf(am, __shfl_xor(am, m, 64));
    if ((tid & 63) == 0) red[tid >> 6] = am;
    __syncthreads();
    am = fmaxf(fmaxf(red[0], red[1]), fmaxf(red[2], red[3]));
    const float sv = fmaxf(am / 127.0f, 1e-8f);
    if (tid == 0) { s[t] = sv; amax_h[t] = 0u; }

    int* out = (int*)(q + (size_t)t * D_DIM);
#pragma unroll
    for (int j = 0; j < 4; j++) {
        float4 v = xv[j];
        out[j * 256 + tid] = q8(v.x, sv) | (q8(v.y, sv) << 8) | (q8(v.z, sv) << 16) | (q8(v.w, sv) << 24);
    }
}

// ---------------------------------------------------------------------------
// Kernel B: per-row int8 weight quant.  1 block per row; row staged in LDS.
// L is 4096 (Wg/Wu) or 11008 (Wd).
// ---------------------------------------------------------------------------
__global__ void wquant(const float* __restrict__ W, int L,
                       char* __restrict__ Wq, float* __restrict__ ws) {
    __shared__ __align__(16) float buf[I_DIM];
    __shared__ float red[4];
    const int r = blockIdx.x, tid = threadIdx.x;
    const float4* row = (const float4*)(W + (size_t)r * L);
    const int n4 = L >> 2;

    float am = 0.0f;
    for (int c = tid; c < n4; c += 256) {
        float4 v = row[c];
        ((float4*)buf)[c] = v;
        am = fmaxf(am, fmaxf(fmaxf(fabsf(v.x), fabsf(v.y)), fmaxf(fabsf(v.z), fabsf(v.w))));
    }
#pragma unroll
    for (int m = 32; m >= 1; m >>= 1) am = fmaxf(am, __shfl_xor(am, m, 64));
    if ((tid & 63) == 0) red[tid >> 6] = am;
    __syncthreads();
    am = fmaxf(fmaxf(red[0], red[1]), fmaxf(red[2], red[3]));
    const float s = fmaxf(am / 127.0f, 1e-8f);
    if (tid == 0) ws[r] = s;

    int* out = (int*)(Wq + (size_t)r * L);
    for (int c = tid; c < n4; c += 256) {
        float4 v = ((float4*)buf)[c];
        out[c] = q8(v.x, s) | (q8(v.y, s) << 8) | (q8(v.z, s) << 16) | (q8(v.w, s) << 24);
    }
}

// ---------------------------------------------------------------------------
// Kernel C: fused gate+up int8 GEMM (NT), 128x128 tile, BK=64, 4 waves (2x2).
// Epilogue: dequant, h = silu(g)*u -> fp32, per-token amax via atomicMax.
// ---------------------------------------------------------------------------
__global__ __launch_bounds__(256, 2) void gemm_gateup(
    const char* __restrict__ qx,    // [T_TOK][D_DIM]
    const char* __restrict__ wgq,   // [I_DIM][D_DIM]
    const char* __restrict__ wuq,   // [I_DIM][D_DIM]
    const float* __restrict__ s,    // [T_TOK]
    const float* __restrict__ wsg,  // [I_DIM]
    const float* __restrict__ wsu,  // [I_DIM]
    float* __restrict__ h,          // [T_TOK][I_DIM]
    unsigned* __restrict__ amax_h)  // [T_TOK]
{
    __shared__ __align__(16) char lsA[128 * 64];
    __shared__ __align__(16) char lsG[128 * 64];
    __shared__ __align__(16) char lsU[128 * 64];

    const int bn = blockIdx.x;            // 0..85  (I tiles)
    const int bm = blockIdx.y;            // 0..63  (token tiles)
    const int tid = threadIdx.x;
    const int lane = tid & 63, wid = tid >> 6;
    const int wm = wid >> 1, wn = wid & 1;

    v4i accG[4][4] = {};
    v4i accU[4][4] = {};

    const int srow = lane >> 2, scol = (lane & 3) * 16;
    const char* Abase = qx  + (size_t)(bm * 128) * D_DIM;
    const char* Gbase = wgq + (size_t)(bn * 128) * D_DIM;
    const char* Ubase = wuq + (size_t)(bn * 128) * D_DIM;

    const int fr = lane & 15, fk = (lane >> 4) * 16;

    for (int k0 = 0; k0 < D_DIM; k0 += 64) {
        for (int c = wid; c < 8; c += 4) {
            const int row = c * 16 + srow;
            async_load16(Abase + (size_t)row * D_DIM + k0 + scol, lsA + c * 1024);
            async_load16(Gbase + (size_t)row * D_DIM + k0 + scol, lsG + c * 1024);
            async_load16(Ubase + (size_t)row * D_DIM + k0 + scol, lsU + c * 1024);
        }
        __syncthreads();

        v4i a[4], bg[4], bu[4];
#pragma unroll
        for (int m = 0; m < 4; m++)
            a[m] = *(const v4i*)(lsA + (wm * 64 + m * 16 + fr) * 64 + fk);
#pragma unroll
        for (int n = 0; n < 4; n++) {
            bg[n] = *(const v4i*)(lsG + (wn * 64 + n * 16 + fr) * 64 + fk);
            bu[n] = *(const v4i*)(lsU + (wn * 64 + n * 16 + fr) * 64 + fk);
        }
#pragma unroll
        for (int m = 0; m < 4; m++)
#pragma unroll
            for (int n = 0; n < 4; n++) {
                accG[m][n] = __builtin_amdgcn_mfma_i32_16x16x64_i8(a[m], bg[n], accG[m][n], 0, 0, 0);
                accU[m][n] = __builtin_amdgcn_mfma_i32_16x16x64_i8(a[m], bu[n], accU[m][n], 0, 0, 0);
            }
        __syncthreads();
    }

    // Epilogue: C row = (lane>>4)*4 + reg, col = lane&15 (within each 16x16 frag)
    const int fq = lane >> 4;
    const int tbase = bm * 128 + wm * 64;
    const int ibase = bn * 128 + wn * 64;
    float wg_[4], wu_[4];
#pragma unroll
    for (int n = 0; n < 4; n++) {
        wg_[n] = wsg[ibase + n * 16 + fr];
        wu_[n] = wsu[ibase + n * 16 + fr];
    }
#pragma unroll
    for (int m = 0; m < 4; m++) {
#pragma unroll
        for (int reg = 0; reg < 4; reg++) {
            const int t = tbase + m * 16 + fq * 4 + reg;
            const float sv = s[t];
            float* hrow = h + (size_t)t * I_DIM + ibase;
            float vmax = 0.0f;
#pragma unroll
            for (int n = 0; n < 4; n++) {
                const float g = (float)accG[m][n][reg] * sv * wg_[n];
                const float u = (float)accU[m][n][reg] * sv * wu_[n];
                const float hv = (g / (1.0f + expf(-g))) * u;  // silu(g)*u
                hrow[n * 16 + fr] = hv;
                vmax = fmaxf(vmax, fabsf(hv));
            }
#pragma unroll
            for (int msk = 1; msk < 16; msk <<= 1)
                vmax = fmaxf(vmax, __shfl_xor(vmax, msk, 64));
            if (fr == 0) atomicMax(amax_h + t, __float_as_uint(vmax));
        }
    }
}

// ---------------------------------------------------------------------------
// Kernel D: per-token int8 quant of h using precomputed amax.
// ---------------------------------------------------------------------------
__global__ void hquant(const float* __restrict__ h, const unsigned* __restrict__ amax_h,
                       char* __restrict__ q2, float* __restrict__ s2) {
    const int t = blockIdx.x, tid = threadIdx.x;
    const float am = __uint_as_float(amax_h[t]);
    const float s = fmaxf(am / 127.0f, 1e-8f);
    if (tid == 0) s2[t] = s;
    const float4* row = (const float4*)(h + (size_t)t * I_DIM);
    int* out = (int*)(q2 + (size_t)t * I_DIM);
    for (int c = tid; c < (I_DIM >> 2); c += 256) {
        float4 v = row[c];
        out[c] = q8(v.x, s) | (q8(v.y, s) << 8) | (q8(v.z, s) << 16) | (q8(v.w, s) << 24);
    }
}

// ---------------------------------------------------------------------------
// Kernel E: down int8 GEMM (NT), 128x128 tile, BK=64.  out = acc * s2 * wsd.
// ---------------------------------------------------------------------------
__global__ __launch_bounds__(256, 2) void gemm_down(
    const char* __restrict__ q2,    // [T_TOK][I_DIM]
    const char* __restrict__ wdq,   // [D_DIM][I_DIM]
    const float* __restrict__ s2,   // [T_TOK]
    const float* __restrict__ wsd,  // [D_DIM]
    float* __restrict__ out)        // [T_TOK][D_DIM]
{
    __shared__ __align__(16) char lsA[128 * 64];
    __shared__ __align__(16) char lsB[128 * 64];

    const int bn = blockIdx.x;            // 0..31 (D tiles)
    const int bm = blockIdx.y;            // 0..63 (token tiles)
    const int tid = threadIdx.x;
    const int lane = tid & 63, wid = tid >> 6;
    const int wm = wid >> 1, wn = wid & 1;

    v4i acc[4][4] = {};

    const int srow = lane >> 2, scol = (lane & 3) * 16;
    const char* Abase = q2  + (size_t)(bm * 128) * I_DIM;
    const char* Bbase = wdq + (size_t)(bn * 128) * I_DIM;

    const int fr = lane & 15, fk = (lane >> 4) * 16;

    for (int k0 = 0; k0 < I_DIM; k0 += 64) {
        for (int c = wid; c < 8; c += 4) {
            const int row = c * 16 + srow;
            async_load16(Abase + (size_t)row * I_DIM + k0 + scol, lsA + c * 1024);
            async_load16(Bbase + (size_t)row * I_DIM + k0 + scol, lsB + c * 1024);
        }
        __syncthreads();

        v4i a[4], b[4];
#pragma unroll
        for (int m = 0; m < 4; m++)
            a[m] = *(const v4i*)(lsA + (wm * 64 + m * 16 + fr) * 64 + fk);
#pragma unroll
        for (int n = 0; n < 4; n++)
            b[n] = *(const v4i*)(lsB + (wn * 64 + n * 16 + fr) * 64 + fk);
#pragma unroll
        for (int m = 0; m < 4; m++)
#pragma unroll
            for (int n = 0; n < 4; n++)
                acc[m][n] = __builtin_amdgcn_mfma_i32_16x16x64_i8(a[m], b[n], acc[m][n], 0, 0, 0);
        __syncthreads();
    }

    const int fq = lane >> 4;
    const int tbase = bm * 128 + wm * 64;
    const int dbase = bn * 128 + wn * 64;
    float wd_[4];
#pragma unroll
    for (int n = 0; n < 4; n++) wd_[n] = wsd[dbase + n * 16 + fr];
#pragma unroll
    for (int m = 0; m < 4; m++) {
#pragma unroll
        for (int reg = 0; reg < 4; reg++) {
            const int t = tbase + m * 16 + fq * 4 + reg;
            const float sv = s2[t];
            float* orow = out + (size_t)t * D_DIM + dbase;
#pragma unroll
            for (int n = 0; n < 4; n++)
                orow[n * 16 + fr] = (float)acc[m][n][reg] * sv * wd_[n];
        }
    }
}

// ---------------------------------------------------------------------------
extern "C" void kernel_launch(void* const* d_in, const int* in_sizes, int n_in,
                              void* d_out, int out_size, void* d_ws, size_t ws_size,
                              hipStream_t stream) {
    const float* x  = (const float*)d_in[0];   // [4,2048,4096]
    const float* rw = (const float*)d_in[1];   // [4096]
    const float* Wg = (const float*)d_in[2];   // [11008,4096]
    const float* Wu = (const float*)d_in[3];   // [11008,4096]
    const float* Wd = (const float*)d_in[4];   // [4096,11008]
    float* out = (float*)d_out;

    char* p = (char*)d_ws;
    auto alloc = [&](size_t bytes) {
        char* r = p;
        p += (bytes + 255) & ~(size_t)255;
        return r;
    };
    char*     qx    = alloc((size_t)T_TOK * D_DIM);          // 33.5 MB
    char*     wgq   = alloc((size_t)I_DIM * D_DIM);          // 45.1 MB
    char*     wuq   = alloc((size_t)I_DIM * D_DIM);          // 45.1 MB
    char*     wdq   = alloc((size_t)D_DIM * I_DIM);          // 45.1 MB
    char*     q2    = alloc((size_t)T_TOK * I_DIM);          // 90.2 MB
    float*    h     = (float*)alloc((size_t)T_TOK * I_DIM * 4); // 360.7 MB
    float*    sAct  = (float*)alloc((size_t)T_TOK * 4);
    float*    s2    = (float*)alloc((size_t)T_TOK * 4);
    unsigned* amaxh = (unsigned*)alloc((size_t)T_TOK * 4);
    float*    wsg   = (float*)alloc((size_t)I_DIM * 4);
    float*    wsu   = (float*)alloc((size_t)I_DIM * 4);
    float*    wsd   = (float*)alloc((size_t)D_DIM * 4);

    rmsnorm_quant<<<T_TOK, 256, 0, stream>>>(x, rw, qx, sAct, amaxh);
    wquant<<<I_DIM, 256, 0, stream>>>(Wg, D_DIM, wgq, wsg);
    wquant<<<I_DIM, 256, 0, stream>>>(Wu, D_DIM, wuq, wsu);
    wquant<<<D_DIM, 256, 0, stream>>>(Wd, I_DIM, wdq, wsd);
    gemm_gateup<<<dim3(I_DIM / 128, T_TOK / 128), 256, 0, stream>>>(
        qx, wgq, wuq, sAct, wsg, wsu, h, amaxh);
    hquant<<<T_TOK, 256, 0, stream>>>(h, amaxh, q2, s2);
    gemm_down<<<dim3(D_DIM / 128, T_TOK / 128), 256, 0, stream>>>(
        q2, wdq, s2, wsd, out);
}